// Round 11
// baseline (427.580 us; speedup 1.0000x reference)
//
#include <hip/hip_runtime.h>
#include <hip/hip_bf16.h>
#include <math.h>

#define NN 16384
#define BB 64
#define NPG 256
#define KNN 100
#define FIN 5
#define HH 128
#define H2 768
#define SLOPE 0.01f

// Inputs are fp32 (verified R3). Dtype detect inline: bn_gamma all-ones -> first 32 bits
// 0x3F800000 (fp32) vs 0x3F803F80 (bf16). One scalar load per kernel, no extra dispatch.
__device__ __forceinline__ int detect_bf(const void* gamma) {
    return ((const unsigned*)gamma)[0] == 0x3F803F80u;
}
__device__ __forceinline__ float loadin(const void* p, size_t i, int bf) {
    return bf ? __bfloat162float(((const __hip_bfloat16*)p)[i]) : ((const float*)p)[i];
}
template <typename T>
__device__ __forceinline__ float ldT(const T* p, size_t i) { return (float)p[i]; }
template <>
__device__ __forceinline__ float ldT<__hip_bfloat16>(const __hip_bfloat16* p, size_t i) {
    return __bfloat162float(p[i]);
}
__device__ __forceinline__ float4 ldT4(const float* p) { return *(const float4*)p; }
__device__ __forceinline__ float4 ldT4(const __hip_bfloat16* p) {
    ushort4 u = *(const ushort4*)p;
    return make_float4(__uint_as_float((unsigned)u.x << 16),
                       __uint_as_float((unsigned)u.y << 16),
                       __uint_as_float((unsigned)u.z << 16),
                       __uint_as_float((unsigned)u.w << 16));
}
__device__ __forceinline__ void stage_chunk(float* dst, const float* src, int n, int t) {
    const float4* s = (const float4*)src;
    float4* d = (float4*)dst;
    int n4 = n >> 2;
    for (int i = t; i < n4; i += 256) d[i] = s[i];
}
__device__ __forceinline__ void stage_chunk(float* dst, const __hip_bfloat16* src, int n, int t) {
    const ushort4* s = (const ushort4*)src;
    int n4 = n >> 2;
    for (int i = t; i < n4; i += 256) {
        ushort4 u = s[i];
        dst[i * 4 + 0] = __uint_as_float((unsigned)u.x << 16);
        dst[i * 4 + 1] = __uint_as_float((unsigned)u.y << 16);
        dst[i * 4 + 2] = __uint_as_float((unsigned)u.z << 16);
        dst[i * 4 + 3] = __uint_as_float((unsigned)u.w << 16);
    }
}

// Order-preserving fp32 <-> u32 map for atomicMax-based max pooling.
__device__ __forceinline__ unsigned enc_f(float f) {
    unsigned u = __float_as_uint(f);
    return (u & 0x80000000u) ? ~u : (u | 0x80000000u);
}
__device__ __forceinline__ float dec_f(unsigned u) {
    return __uint_as_float((u & 0x80000000u) ? (u & 0x7FFFFFFFu) : ~u);
}

// ---------------- cvt + g pool-accumulator init ----------------
// g[b][c]: within each 256-col conv chunk, cols 0..127 = mean accum (0.0f),
// cols 128..255 = encoded max accum (enc(-inf) = 0x007FFFFF).
__global__ void cvt_kernel(const void* in, const void* gamma, float* __restrict__ out,
                           int n, float* __restrict__ g) {
    int i = blockIdx.x * 256 + threadIdx.x;
    int bf = detect_bf(gamma);
    if (i < n) out[i] = loadin(in, i, bf);
    if (i < BB * H2) {
        int cm = i & 255;
        g[i] = (cm < 128) ? 0.0f : __uint_as_float(0x007FFFFFu);
    }
}

// ---------------- KNN v2 + 4 accumulators (break the addc dependency chain) -------------
// u64-key rank count. key_j = (bits(d2_j) << 32) | j; rank = #{key < mykey} == stable
// top-k (lower index wins ties), matching jax.lax.top_k.
__global__ void knn_kernel(const float* __restrict__ xf, unsigned char* __restrict__ nbr) {
    int row = blockIdx.x;
    int b = row >> 8, il = row & 255;
    int j = threadIdx.x;
    __shared__ float xg[NPG * FIN];
    __shared__ __align__(16) unsigned long long keys[NPG];
    for (int idx = threadIdx.x; idx < NPG * FIN; idx += 256)
        xg[idx] = xf[(size_t)b * NPG * FIN + idx];
    __syncthreads();
    float xi0 = xg[il*FIN+0], xi1 = xg[il*FIN+1], xi2 = xg[il*FIN+2],
          xi3 = xg[il*FIN+3], xi4 = xg[il*FIN+4];
    float d0 = xi0 - xg[j*FIN+0];
    float d1 = xi1 - xg[j*FIN+1];
    float d2_ = xi2 - xg[j*FIN+2];
    float d3 = xi3 - xg[j*FIN+3];
    float d4 = xi4 - xg[j*FIN+4];
    float dd = d0*d0;
    dd += d1*d1; dd += d2_*d2_; dd += d3*d3; dd += d4*d4;
    if (j == il) dd = 1e30f;
    unsigned long long mykey = ((unsigned long long)__float_as_uint(dd) << 32)
                             | (unsigned long long)j;
    keys[j] = mykey;
    __syncthreads();
    const ulonglong2* kp = (const ulonglong2*)keys;
    int c0 = 0, c1 = 0, c2 = 0, c3 = 0;
    #pragma unroll 8
    for (int q = 0; q < NPG / 2; q += 2) {
        ulonglong2 ka = kp[q];
        ulonglong2 kb = kp[q + 1];
        c0 += (ka.x < mykey) ? 1 : 0;
        c1 += (ka.y < mykey) ? 1 : 0;
        c2 += (kb.x < mykey) ? 1 : 0;
        c3 += (kb.y < mykey) ? 1 : 0;
    }
    int cnt = (c0 + c1) + (c2 + c3);
    if (cnt < KNN) nbr[(size_t)row * KNN + cnt] = (unsigned char)j;
}

// ---------------- aggregation, C=5, BOTH hops fused ----------------
__global__ void agg5x2_kernel(const float* __restrict__ hin,
                              const unsigned char* __restrict__ nbr,
                              float* __restrict__ t5a, float* __restrict__ t5b, float nrm) {
    int b = blockIdx.x, i = threadIdx.x;
    __shared__ float xs[NPG * FIN];
    __shared__ float ys[NPG * FIN];
    for (int idx = threadIdx.x; idx < NPG * FIN; idx += 256)
        xs[idx] = hin[(size_t)b * NPG * FIN + idx];
    __syncthreads();
    const unsigned char* nb = nbr + (size_t)(b * NPG + i) * KNN;
    float a0=0.f, a1=0.f, a2=0.f, a3=0.f, a4=0.f;
    for (int k = 0; k < KNN; ++k) {
        int base = (int)nb[k] * FIN;
        a0 += xs[base+0]; a1 += xs[base+1]; a2 += xs[base+2];
        a3 += xs[base+3]; a4 += xs[base+4];
    }
    a0 *= nrm; a1 *= nrm; a2 *= nrm; a3 *= nrm; a4 *= nrm;
    size_t o = (size_t)(b * NPG + i) * FIN;
    t5a[o+0] = a0; t5a[o+1] = a1; t5a[o+2] = a2; t5a[o+3] = a3; t5a[o+4] = a4;
    ys[i*FIN+0] = a0; ys[i*FIN+1] = a1; ys[i*FIN+2] = a2;
    ys[i*FIN+3] = a3; ys[i*FIN+4] = a4;
    __syncthreads();
    a0=0.f; a1=0.f; a2=0.f; a3=0.f; a4=0.f;
    for (int k = 0; k < KNN; ++k) {
        int base = (int)nb[k] * FIN;
        a0 += ys[base+0]; a1 += ys[base+1]; a2 += ys[base+2];
        a3 += ys[base+3]; a4 += ys[base+4];
    }
    t5b[o+0] = nrm*a0; t5b[o+1] = nrm*a1; t5b[o+2] = nrm*a2;
    t5b[o+3] = nrm*a3; t5b[o+4] = nrm*a4;
}

// ---------------- aggregation, C=128: conflict-free oct gather ----------------
__global__ void agg128_kernel(const float* __restrict__ hin, const unsigned char* __restrict__ nbr,
                              float* __restrict__ hout, float nrm) {
    int b = blockIdx.x;
    int c0 = blockIdx.y * 32;
    int i0 = blockIdx.z * 64;
    __shared__ float hs[NPG * 36];
    int t = threadIdx.x;
    for (int i = t; i < NPG * 8; i += 256) {
        int node = i >> 3, grp = i & 7;
        float4 v = *(const float4*)&hin[((size_t)(b * NPG + node)) * HH + c0 + grp * 4];
        *(float4*)&hs[node * 36 + grp * 4] = v;
    }
    __syncthreads();
    int oct = t & 7;
    #pragma unroll
    for (int pass = 0; pass < 2; ++pass) {
        int il = i0 + pass * 32 + (t >> 3);
        const unsigned char* nb = nbr + (size_t)(b * NPG + il) * KNN;
        float a0 = 0.f, a1 = 0.f, a2 = 0.f, a3 = 0.f;
        #pragma unroll 5
        for (int k4 = 0; k4 < KNN / 4; ++k4) {
            uchar4 n4 = *(const uchar4*)&nb[k4 * 4];
            const float4 v0 = *(const float4*)&hs[(int)n4.x * 36 + oct * 4];
            const float4 v1 = *(const float4*)&hs[(int)n4.y * 36 + oct * 4];
            const float4 v2 = *(const float4*)&hs[(int)n4.z * 36 + oct * 4];
            const float4 v3 = *(const float4*)&hs[(int)n4.w * 36 + oct * 4];
            a0 += v0.x + v1.x + v2.x + v3.x;
            a1 += v0.y + v1.y + v2.y + v3.y;
            a2 += v0.z + v1.z + v2.z + v3.z;
            a3 += v0.w + v1.w + v2.w + v3.w;
        }
        float4 o = make_float4(nrm * a0, nrm * a1, nrm * a2, nrm * a3);
        *(float4*)&hout[((size_t)(b * NPG + il)) * HH + c0 + oct * 4] = o;
    }
}

// ---------------- pool epilogue: shuffle-reduce over 16-lane groups + atomics ------------
// Threads t = cg*16 + rp (rp = t&15 are 16 CONSECUTIVE lanes of one wave). sv = sum
// partial (pre-scaled by 1/NPG), mv = max partial, 8 cols each. After xor-reduce over
// rp, lane rp==0 commits: atomicAdd for mean, atomicMax on enc() for max.
__device__ __forceinline__ void pool_epilogue(float* g, int b, int gc0, int cg, int rp,
                                              float* sv, float* mv) {
    #pragma unroll
    for (int mask = 1; mask < 16; mask <<= 1) {
        #pragma unroll
        for (int i = 0; i < 8; ++i) {
            sv[i] += __shfl_xor(sv[i], mask);
            mv[i] = fmaxf(mv[i], __shfl_xor(mv[i], mask));
        }
    }
    if (rp == 0) {
        #pragma unroll
        for (int i = 0; i < 8; ++i) {
            atomicAdd(&g[(size_t)b * H2 + gc0 + cg * 8 + i], sv[i]);
            atomicMax((unsigned*)&g[(size_t)b * H2 + gc0 + HH + cg * 8 + i], enc_f(mv[i]));
        }
    }
}

// ---------------- tagmm5 (+fused pool): O = leaky(X0@W0+X1@W1+X2@W2+b) ----------------
template <typename T>
__device__ __forceinline__ void tagmm5_body(
        const float* __restrict__ X0, const float* __restrict__ X1,
        const float* __restrict__ X2,
        const T* __restrict__ W, const T* __restrict__ bias,
        float* __restrict__ O, float* g, float* Ws, float* Xs) {
    int t = threadIdx.x;
    int r0 = blockIdx.x * 16;
    int r = t & 15, cg = t >> 4;
    float acc[8] = {0.f,0.f,0.f,0.f,0.f,0.f,0.f,0.f};
    const float* Xh[3] = {X0, X1, X2};
    for (int h = 0; h < 3; ++h) {
        const float* X = Xh[h];
        stage_chunk(Ws, W + (size_t)h * FIN * HH, FIN * HH, t);
        for (int idx = t; idx < 16 * FIN; idx += 256) {
            int rr = idx / FIN, k = idx - rr * FIN;
            Xs[rr * 9 + k] = X[(size_t)(r0 + rr) * FIN + k];
        }
        __syncthreads();
        #pragma unroll
        for (int k = 0; k < FIN; ++k) {
            float xv = Xs[r * 9 + k];
            const float4 wa = *(const float4*)&Ws[k * HH + cg * 8];
            const float4 wb = *(const float4*)&Ws[k * HH + cg * 8 + 4];
            acc[0] += xv * wa.x; acc[1] += xv * wa.y;
            acc[2] += xv * wa.z; acc[3] += xv * wa.w;
            acc[4] += xv * wb.x; acc[5] += xv * wb.y;
            acc[6] += xv * wb.z; acc[7] += xv * wb.w;
        }
        __syncthreads();
    }
    size_t orow = (size_t)(r0 + r) * HH + cg * 8;
    float sv[8], mv[8];
    #pragma unroll
    for (int m = 0; m < 8; ++m) {
        float v = acc[m] + ldT(bias, cg * 8 + m);
        v = v > 0.f ? v : SLOPE * v;
        O[orow + m] = v;
        sv[m] = v * (1.0f / NPG);
        mv[m] = v;
    }
    pool_epilogue(g, r0 >> 8, 0, cg, r, sv, mv);
}

__global__ __launch_bounds__(256) void tagmm5_kernel(
        const float* X0, const float* X1, const float* X2,
        const void* W, const void* bias, float* O, float* g, const void* gamma) {
    __shared__ float Ws[FIN * HH];
    __shared__ float Xs[16 * 9];
    if (detect_bf(gamma))
        tagmm5_body<__hip_bfloat16>(X0, X1, X2, (const __hip_bfloat16*)W,
                                    (const __hip_bfloat16*)bias, O, g, Ws, Xs);
    else
        tagmm5_body<float>(X0, X1, X2, (const float*)W, (const float*)bias, O, g, Ws, Xs);
}

// ---------------- tagmm128 v2 (+fused pool): 32 rows x 128 cols, Xs transposed ------------
template <typename T>
__device__ __forceinline__ void tagmm128_body(
        const float* __restrict__ X0, const float* __restrict__ X1,
        const float* __restrict__ X2,
        const T* __restrict__ W, const T* __restrict__ bias,
        float* __restrict__ O, float* g, int gc0, float* Ws, float* Xs) {
    int t = threadIdx.x;
    int r0 = blockIdx.x * 32;
    int rp = t & 15, cg = t >> 4;        // row pair (2 rows), 8-col group
    float acc[16];
    #pragma unroll
    for (int m = 0; m < 16; ++m) acc[m] = 0.f;
    const float* Xh[3] = {X0, X1, X2};
    for (int h = 0; h < 3; ++h) {
        const float* X = Xh[h];
        for (int k0 = 0; k0 < HH; k0 += 64) {
            stage_chunk(Ws, W + ((size_t)h * HH + k0) * HH, 64 * HH, t);
            for (int i = t; i < 32 * 16; i += 256) {
                int row = i & 31, kq = i >> 5;
                float4 v = *(const float4*)&X[(size_t)(r0 + row) * HH + k0 + kq * 4];
                Xs[(kq * 4 + 0) * 34 + row] = v.x;
                Xs[(kq * 4 + 1) * 34 + row] = v.y;
                Xs[(kq * 4 + 2) * 34 + row] = v.z;
                Xs[(kq * 4 + 3) * 34 + row] = v.w;
            }
            __syncthreads();
            #pragma unroll 8
            for (int k = 0; k < 64; ++k) {
                const float2 xv = *(const float2*)&Xs[k * 34 + rp * 2];
                const float4 wa = *(const float4*)&Ws[k * HH + cg * 8];
                const float4 wb = *(const float4*)&Ws[k * HH + cg * 8 + 4];
                acc[0] += xv.x * wa.x; acc[1] += xv.x * wa.y;
                acc[2] += xv.x * wa.z; acc[3] += xv.x * wa.w;
                acc[4] += xv.x * wb.x; acc[5] += xv.x * wb.y;
                acc[6] += xv.x * wb.z; acc[7] += xv.x * wb.w;
                acc[8]  += xv.y * wa.x; acc[9]  += xv.y * wa.y;
                acc[10] += xv.y * wa.z; acc[11] += xv.y * wa.w;
                acc[12] += xv.y * wb.x; acc[13] += xv.y * wb.y;
                acc[14] += xv.y * wb.z; acc[15] += xv.y * wb.w;
            }
            __syncthreads();
        }
    }
    float sv[8], mv[8];
    #pragma unroll
    for (int rr = 0; rr < 2; ++rr) {
        size_t orow = (size_t)(r0 + rp * 2 + rr) * HH + cg * 8;
        #pragma unroll
        for (int m = 0; m < 8; ++m) {
            float v = acc[rr * 8 + m] + ldT(bias, cg * 8 + m);
            v = v > 0.f ? v : SLOPE * v;
            O[orow + m] = v;
            if (rr == 0) { sv[m] = v * (1.0f / NPG); mv[m] = v; }
            else         { sv[m] += v * (1.0f / NPG); mv[m] = fmaxf(mv[m], v); }
        }
    }
    pool_epilogue(g, r0 >> 8, gc0, cg, rp, sv, mv);
}

__global__ __launch_bounds__(256) void tagmm128_kernel(
        const float* X0, const float* X1, const float* X2,
        const void* W, const void* bias, float* O, float* g, int gc0, const void* gamma) {
    __shared__ float Ws[64 * HH];     // 32 KB
    __shared__ float Xs[64 * 34];     // 8.7 KB
    if (detect_bf(gamma))
        tagmm128_body<__hip_bfloat16>(X0, X1, X2, (const __hip_bfloat16*)W,
                                      (const __hip_bfloat16*)bias, O, g, gc0, Ws, Xs);
    else
        tagmm128_body<float>(X0, X1, X2, (const float*)W, (const float*)bias,
                             O, g, gc0, Ws, Xs);
}

// ---------------- batchnorm over batch dim (64): decode pool accumulators ----------------
__global__ void bn_kernel(float* __restrict__ g, const void* gamma, const void* beta) {
    int c = blockIdx.x * 128 + threadIdx.x;
    int bf = detect_bf(gamma);
    int ismax = (c & 255) >= 128;
    float vals[BB];
    float mu = 0.f;
    for (int b = 0; b < BB; ++b) {
        float raw = g[(size_t)b * H2 + c];
        float x = ismax ? dec_f(__float_as_uint(raw)) : raw;
        vals[b] = x;
        mu += x;
    }
    mu *= (1.0f / BB);
    float var = 0.f;
    for (int b = 0; b < BB; ++b) {
        float d = vals[b] - mu;
        var += d * d;
    }
    var *= (1.0f / BB);
    float rs = 1.0f / sqrtf(var + 1e-5f);
    float ga = loadin(gamma, c, bf), be = loadin(beta, c, bf);
    for (int b = 0; b < BB; ++b)
        g[(size_t)b * H2 + c] = (vals[b] - mu) * rs * ga + be;
}

// ---------------- MLP layer GEMM: double-buffered prefetch ----------------
template <typename T>
__device__ __forceinline__ void mlp_layer_body(
        const float* __restrict__ X, const T* __restrict__ W, const T* __restrict__ bias,
        float* __restrict__ O, float* Xs0, float* Xs1, float* Ws0, float* Ws1) {
    int t = threadIdx.x;
    int col0 = blockIdx.x * 16;
    int r = t & 63, cg = t >> 6;
    float acc[4] = {0.f, 0.f, 0.f, 0.f};
    const float4* Xg = (const float4*)X;
    float4 xr[4]; float4 wr;
    int kr = t >> 2, c4 = t & 3;
    #pragma unroll
    for (int u = 0; u < 4; ++u) {
        int i = t + u * 256;
        xr[u] = Xg[(size_t)(i >> 4) * (H2 / 4) + (i & 15)];
    }
    wr = ldT4(W + (size_t)kr * H2 + col0 + c4 * 4);
    {
        #pragma unroll
        for (int u = 0; u < 4; ++u) {
            int i = t + u * 256;
            float* d = &Xs0[(i >> 4) * 65 + (i & 15) * 4];
            d[0] = xr[u].x; d[1] = xr[u].y; d[2] = xr[u].z; d[3] = xr[u].w;
        }
        float* d = &Ws0[kr * 16 + c4 * 4];
        d[0] = wr.x; d[1] = wr.y; d[2] = wr.z; d[3] = wr.w;
    }
    __syncthreads();
    for (int s = 0; s < 12; ++s) {
        if (s + 1 < 12) {
            int k0 = (s + 1) * 64;
            #pragma unroll
            for (int u = 0; u < 4; ++u) {
                int i = t + u * 256;
                xr[u] = Xg[(size_t)(i >> 4) * (H2 / 4) + (k0 >> 2) + (i & 15)];
            }
            wr = ldT4(W + (size_t)(k0 + kr) * H2 + col0 + c4 * 4);
        }
        const float* Xc = (s & 1) ? Xs1 : Xs0;
        const float* Wc = (s & 1) ? Ws1 : Ws0;
        #pragma unroll 8
        for (int k = 0; k < 64; ++k) {
            float xv = Xc[r * 65 + k];
            const float4 wv = *(const float4*)&Wc[k * 16 + cg * 4];
            acc[0] += xv * wv.x; acc[1] += xv * wv.y;
            acc[2] += xv * wv.z; acc[3] += xv * wv.w;
        }
        if (s + 1 < 12) {
            float* Xn = (s & 1) ? Xs0 : Xs1;
            float* Wn = (s & 1) ? Ws0 : Ws1;
            #pragma unroll
            for (int u = 0; u < 4; ++u) {
                int i = t + u * 256;
                float* d = &Xn[(i >> 4) * 65 + (i & 15) * 4];
                d[0] = xr[u].x; d[1] = xr[u].y; d[2] = xr[u].z; d[3] = xr[u].w;
            }
            float* d = &Wn[kr * 16 + c4 * 4];
            d[0] = wr.x; d[1] = wr.y; d[2] = wr.z; d[3] = wr.w;
            __syncthreads();
        }
    }
    size_t o = (size_t)r * H2 + col0 + cg * 4;
    #pragma unroll
    for (int m = 0; m < 4; ++m) {
        float v = acc[m] + ldT(bias, col0 + cg * 4 + m);
        O[o + m] = v > 0.f ? v : SLOPE * v;
    }
}

__global__ __launch_bounds__(256) void mlp_layer_kernel(
        const float* X, const void* W, size_t woff, const void* bias, size_t boff,
        float* O, const void* gamma) {
    __shared__ float Xs0[64 * 65], Xs1[64 * 65];
    __shared__ float Ws0[64 * 16], Ws1[64 * 16];
    if (detect_bf(gamma))
        mlp_layer_body<__hip_bfloat16>(X, (const __hip_bfloat16*)W + woff,
                                       (const __hip_bfloat16*)bias + boff, O,
                                       Xs0, Xs1, Ws0, Ws1);
    else
        mlp_layer_body<float>(X, (const float*)W + woff,
                              (const float*)bias + boff, O, Xs0, Xs1, Ws0, Ws1);
}

// ---------------- final dot: out[b] = X[b,:] . w + ob ----------------
__global__ void final_kernel(const float* __restrict__ X, const void* w, const void* ob,
                             void* out, const void* gamma) {
    int b = blockIdx.x, t = threadIdx.x;
    int bf = detect_bf(gamma);
    float p = 0.f;
    for (int j = t; j < H2; j += 256)
        p += X[(size_t)b * H2 + j] * loadin(w, j, bf);
    __shared__ float red[256];
    red[t] = p;
    __syncthreads();
    for (int s = 128; s > 0; s >>= 1) {
        if (t < s) red[t] += red[t + s];
        __syncthreads();
    }
    if (t == 0) {
        float v = red[0] + loadin(ob, 0, bf);
        if (bf) ((__hip_bfloat16*)out)[b] = __float2bfloat16(v);
        else    ((float*)out)[b] = v;
    }
}

extern "C" void kernel_launch(void* const* d_in, const int* in_sizes, int n_in,
                              void* d_out, int out_size, void* d_ws, size_t ws_size,
                              hipStream_t stream) {
    const void* x_in = d_in[0];
    const void* c1w = d_in[2];  const void* c1b = d_in[3];
    const void* c2w = d_in[4];  const void* c2b = d_in[5];
    const void* c3w = d_in[6];  const void* c3b = d_in[7];
    const void* gam = d_in[8];  const void* bet = d_in[9];
    const void* lw  = d_in[10]; const void* lb  = d_in[11];
    const void* ow  = d_in[12]; const void* obb = d_in[13];

    char* w = (char*)d_ws;
    float* xf = (float*)w;                   w += (size_t)NN * FIN * 4;
    unsigned char* nbr = (unsigned char*)w;  w += (size_t)NN * KNN;
    float* t5a = (float*)w;                  w += (size_t)NN * FIN * 4;
    float* t5b = (float*)w;                  w += (size_t)NN * FIN * 4;
    float* bufA = (float*)w;                 w += (size_t)NN * HH * 4;
    float* bufB = (float*)w;                 w += (size_t)NN * HH * 4;
    float* bufC = (float*)w;                 w += (size_t)NN * HH * 4;
    float* bufD = (float*)w;                 w += (size_t)NN * HH * 4;
    float* g = (float*)w;                    w += (size_t)BB * H2 * 4;
    float* mA = (float*)w;                   w += (size_t)BB * H2 * 4;
    float* mB = (float*)w;                   w += (size_t)BB * H2 * 4;

    float dinv = 1.0f / sqrtf((float)KNN);
    float nrm = dinv * dinv;

    cvt_kernel<<<(NN * FIN + 255) / 256, 256, 0, stream>>>(x_in, gam, xf, NN * FIN, g);
    knn_kernel<<<NN, 256, 0, stream>>>(xf, nbr);

    dim3 conv_grid32(NN / 32);
    dim3 agg_grid(BB, 4, 4);

    // ---- conv1 (Cin=5): hops, then fused matmul+pool ----
    agg5x2_kernel<<<BB, 256, 0, stream>>>(xf, nbr, t5a, t5b, nrm);
    tagmm5_kernel<<<NN / 16, 256, 0, stream>>>(xf, t5a, t5b, c1w, c1b, bufA, g, gam);

    // ---- conv2: bufA -> bufD (+pool @256) ----
    agg128_kernel<<<agg_grid, 256, 0, stream>>>(bufA, nbr, bufB, nrm);
    agg128_kernel<<<agg_grid, 256, 0, stream>>>(bufB, nbr, bufC, nrm);
    tagmm128_kernel<<<conv_grid32, 256, 0, stream>>>(bufA, bufB, bufC, c2w, c2b,
                                                     bufD, g, 256, gam);

    // ---- conv3: bufD -> bufC (+pool @512) ----
    agg128_kernel<<<agg_grid, 256, 0, stream>>>(bufD, nbr, bufA, nrm);
    agg128_kernel<<<agg_grid, 256, 0, stream>>>(bufA, nbr, bufB, nrm);
    tagmm128_kernel<<<conv_grid32, 256, 0, stream>>>(bufD, bufA, bufB, c3w, c3b,
                                                     bufC, g, 512, gam);

    // ---- batchnorm (decodes pool accumulators) ----
    bn_kernel<<<6, 128, 0, stream>>>(g, gam, bet);

    // ---- MLP: 5 GEMM layers, then final dot ----
    float* src = g;
    for (int i = 0; i < 5; ++i) {
        float* dst = (i % 2 == 0) ? mA : mB;
        mlp_layer_kernel<<<H2 / 16, 256, 0, stream>>>(src, lw, (size_t)i * H2 * H2,
                                                      lb, (size_t)i * H2, dst, gam);
        src = dst;
    }
    final_kernel<<<BB, 256, 0, stream>>>(src, ow, obb, d_out, gam);
}

// Round 12
// 409.198 us; speedup vs baseline: 1.0449x; 1.0449x over previous
//
#include <hip/hip_runtime.h>
#include <hip/hip_bf16.h>
#include <math.h>

#define NN 16384
#define BB 64
#define NPG 256
#define KNN 100
#define FIN 5
#define HH 128
#define H2 768
#define SLOPE 0.01f

// Inputs are fp32 (verified R3). Dtype detect inline: bn_gamma all-ones -> first 32 bits
// 0x3F800000 (fp32) vs 0x3F803F80 (bf16). One scalar load per kernel, no extra dispatch.
__device__ __forceinline__ int detect_bf(const void* gamma) {
    return ((const unsigned*)gamma)[0] == 0x3F803F80u;
}
__device__ __forceinline__ float loadin(const void* p, size_t i, int bf) {
    return bf ? __bfloat162float(((const __hip_bfloat16*)p)[i]) : ((const float*)p)[i];
}
template <typename T>
__device__ __forceinline__ float ldT(const T* p, size_t i) { return (float)p[i]; }
template <>
__device__ __forceinline__ float ldT<__hip_bfloat16>(const __hip_bfloat16* p, size_t i) {
    return __bfloat162float(p[i]);
}
__device__ __forceinline__ float4 ldT4(const float* p) { return *(const float4*)p; }
__device__ __forceinline__ float4 ldT4(const __hip_bfloat16* p) {
    ushort4 u = *(const ushort4*)p;
    return make_float4(__uint_as_float((unsigned)u.x << 16),
                       __uint_as_float((unsigned)u.y << 16),
                       __uint_as_float((unsigned)u.z << 16),
                       __uint_as_float((unsigned)u.w << 16));
}
__device__ __forceinline__ void stage_chunk(float* dst, const float* src, int n, int t) {
    const float4* s = (const float4*)src;
    float4* d = (float4*)dst;
    int n4 = n >> 2;
    for (int i = t; i < n4; i += 256) d[i] = s[i];
}
__device__ __forceinline__ void stage_chunk(float* dst, const __hip_bfloat16* src, int n, int t) {
    const ushort4* s = (const ushort4*)src;
    int n4 = n >> 2;
    for (int i = t; i < n4; i += 256) {
        ushort4 u = s[i];
        dst[i * 4 + 0] = __uint_as_float((unsigned)u.x << 16);
        dst[i * 4 + 1] = __uint_as_float((unsigned)u.y << 16);
        dst[i * 4 + 2] = __uint_as_float((unsigned)u.z << 16);
        dst[i * 4 + 3] = __uint_as_float((unsigned)u.w << 16);
    }
}

// Order-preserving fp32 <-> u32 map for atomicMax-based max pooling.
__device__ __forceinline__ unsigned enc_f(float f) {
    unsigned u = __float_as_uint(f);
    return (u & 0x80000000u) ? ~u : (u | 0x80000000u);
}
__device__ __forceinline__ float dec_f(unsigned u) {
    return __uint_as_float((u & 0x80000000u) ? (u & 0x7FFFFFFFu) : ~u);
}

// ---------------- cvt + g pool-accumulator init ----------------
__global__ void cvt_kernel(const void* in, const void* gamma, float* __restrict__ out,
                           int n, float* __restrict__ g) {
    int i = blockIdx.x * 256 + threadIdx.x;
    int bf = detect_bf(gamma);
    if (i < n) out[i] = loadin(in, i, bf);
    if (i < BB * H2) {
        int cm = i & 255;
        g[i] = (cm < 128) ? 0.0f : __uint_as_float(0x007FFFFFu);
    }
}

// ---------------- KNN v4: bitonic sort of u64 keys ----------------
// key_j = (bits(d2_j) << 32) | j  -- keys are DISTINCT (index in low bits), so a full
// ascending sort reproduces rank-count / jax.lax.top_k stable order exactly. 256-element
// bitonic network: 36 compare-exchange stages (33 intra-wave via __shfl_xor, 3 cross-wave
// via LDS). Replaces the O(N) per-thread rank-count loop (~1150 VALU) with ~300 VALU.
// After sort, thread tid holds the tid-th smallest -> byte-coalesced top-100 write.
__global__ __launch_bounds__(256) void knn_kernel(const float* __restrict__ xf,
                                                  unsigned char* __restrict__ nbr) {
    int row = blockIdx.x;
    int b = row >> 8, il = row & 255;
    int tid = threadIdx.x;
    __shared__ float xg[NPG * FIN];
    __shared__ unsigned long long keys[NPG];
    for (int idx = tid; idx < NPG * FIN; idx += 256)
        xg[idx] = xf[(size_t)b * NPG * FIN + idx];
    __syncthreads();
    float xi0 = xg[il*FIN+0], xi1 = xg[il*FIN+1], xi2 = xg[il*FIN+2],
          xi3 = xg[il*FIN+3], xi4 = xg[il*FIN+4];
    float d0 = xi0 - xg[tid*FIN+0];
    float d1 = xi1 - xg[tid*FIN+1];
    float d2_ = xi2 - xg[tid*FIN+2];
    float d3 = xi3 - xg[tid*FIN+3];
    float d4 = xi4 - xg[tid*FIN+4];
    float dd = d0*d0;
    dd += d1*d1; dd += d2_*d2_; dd += d3*d3; dd += d4*d4;
    if (tid == il) dd = 1e30f;               // exclude self -> sorts to the end
    unsigned long long k = ((unsigned long long)__float_as_uint(dd) << 32)
                         | (unsigned long long)tid;
    // bitonic sort, ascending across the 256 threads
    #pragma unroll
    for (int kk = 2; kk <= NPG; kk <<= 1) {
        #pragma unroll
        for (int j = kk >> 1; j > 0; j >>= 1) {
            unsigned long long pk;
            if (j < 64) {
                pk = __shfl_xor(k, j, 64);
            } else {
                __syncthreads();
                keys[tid] = k;
                __syncthreads();
                pk = keys[tid ^ j];
            }
            bool up = ((tid & kk) == 0);
            unsigned long long mn = (k < pk) ? k : pk;
            unsigned long long mx = (k < pk) ? pk : k;
            k = ((tid & j) == 0) ? (up ? mn : mx) : (up ? mx : mn);
        }
    }
    if (tid < KNN)
        nbr[(size_t)row * KNN + tid] = (unsigned char)(k & 0xffu);
}

// ---------------- aggregation, C=5, BOTH hops fused ----------------
__global__ void agg5x2_kernel(const float* __restrict__ hin,
                              const unsigned char* __restrict__ nbr,
                              float* __restrict__ t5a, float* __restrict__ t5b, float nrm) {
    int b = blockIdx.x, i = threadIdx.x;
    __shared__ float xs[NPG * FIN];
    __shared__ float ys[NPG * FIN];
    for (int idx = threadIdx.x; idx < NPG * FIN; idx += 256)
        xs[idx] = hin[(size_t)b * NPG * FIN + idx];
    __syncthreads();
    const unsigned char* nb = nbr + (size_t)(b * NPG + i) * KNN;
    float a0=0.f, a1=0.f, a2=0.f, a3=0.f, a4=0.f;
    for (int k = 0; k < KNN; ++k) {
        int base = (int)nb[k] * FIN;
        a0 += xs[base+0]; a1 += xs[base+1]; a2 += xs[base+2];
        a3 += xs[base+3]; a4 += xs[base+4];
    }
    a0 *= nrm; a1 *= nrm; a2 *= nrm; a3 *= nrm; a4 *= nrm;
    size_t o = (size_t)(b * NPG + i) * FIN;
    t5a[o+0] = a0; t5a[o+1] = a1; t5a[o+2] = a2; t5a[o+3] = a3; t5a[o+4] = a4;
    ys[i*FIN+0] = a0; ys[i*FIN+1] = a1; ys[i*FIN+2] = a2;
    ys[i*FIN+3] = a3; ys[i*FIN+4] = a4;
    __syncthreads();
    a0=0.f; a1=0.f; a2=0.f; a3=0.f; a4=0.f;
    for (int k = 0; k < KNN; ++k) {
        int base = (int)nb[k] * FIN;
        a0 += ys[base+0]; a1 += ys[base+1]; a2 += ys[base+2];
        a3 += ys[base+3]; a4 += ys[base+4];
    }
    t5b[o+0] = nrm*a0; t5b[o+1] = nrm*a1; t5b[o+2] = nrm*a2;
    t5b[o+3] = nrm*a3; t5b[o+4] = nrm*a4;
}

// ---------------- aggregation, C=128: conflict-free oct gather ----------------
__global__ void agg128_kernel(const float* __restrict__ hin, const unsigned char* __restrict__ nbr,
                              float* __restrict__ hout, float nrm) {
    int b = blockIdx.x;
    int c0 = blockIdx.y * 32;
    int i0 = blockIdx.z * 64;
    __shared__ float hs[NPG * 36];
    int t = threadIdx.x;
    for (int i = t; i < NPG * 8; i += 256) {
        int node = i >> 3, grp = i & 7;
        float4 v = *(const float4*)&hin[((size_t)(b * NPG + node)) * HH + c0 + grp * 4];
        *(float4*)&hs[node * 36 + grp * 4] = v;
    }
    __syncthreads();
    int oct = t & 7;
    #pragma unroll
    for (int pass = 0; pass < 2; ++pass) {
        int il = i0 + pass * 32 + (t >> 3);
        const unsigned char* nb = nbr + (size_t)(b * NPG + il) * KNN;
        float a0 = 0.f, a1 = 0.f, a2 = 0.f, a3 = 0.f;
        #pragma unroll 5
        for (int k4 = 0; k4 < KNN / 4; ++k4) {
            uchar4 n4 = *(const uchar4*)&nb[k4 * 4];
            const float4 v0 = *(const float4*)&hs[(int)n4.x * 36 + oct * 4];
            const float4 v1 = *(const float4*)&hs[(int)n4.y * 36 + oct * 4];
            const float4 v2 = *(const float4*)&hs[(int)n4.z * 36 + oct * 4];
            const float4 v3 = *(const float4*)&hs[(int)n4.w * 36 + oct * 4];
            a0 += v0.x + v1.x + v2.x + v3.x;
            a1 += v0.y + v1.y + v2.y + v3.y;
            a2 += v0.z + v1.z + v2.z + v3.z;
            a3 += v0.w + v1.w + v2.w + v3.w;
        }
        float4 o = make_float4(nrm * a0, nrm * a1, nrm * a2, nrm * a3);
        *(float4*)&hout[((size_t)(b * NPG + il)) * HH + c0 + oct * 4] = o;
    }
}

// ---------------- pool epilogue: shuffle-reduce over 16-lane groups + atomics ------------
__device__ __forceinline__ void pool_epilogue(float* g, int b, int gc0, int cg, int rp,
                                              float* sv, float* mv) {
    #pragma unroll
    for (int mask = 1; mask < 16; mask <<= 1) {
        #pragma unroll
        for (int i = 0; i < 8; ++i) {
            sv[i] += __shfl_xor(sv[i], mask);
            mv[i] = fmaxf(mv[i], __shfl_xor(mv[i], mask));
        }
    }
    if (rp == 0) {
        #pragma unroll
        for (int i = 0; i < 8; ++i) {
            atomicAdd(&g[(size_t)b * H2 + gc0 + cg * 8 + i], sv[i]);
            atomicMax((unsigned*)&g[(size_t)b * H2 + gc0 + HH + cg * 8 + i], enc_f(mv[i]));
        }
    }
}

// ---------------- tagmm5 (+fused pool) ----------------
template <typename T>
__device__ __forceinline__ void tagmm5_body(
        const float* __restrict__ X0, const float* __restrict__ X1,
        const float* __restrict__ X2,
        const T* __restrict__ W, const T* __restrict__ bias,
        float* __restrict__ O, float* g, float* Ws, float* Xs) {
    int t = threadIdx.x;
    int r0 = blockIdx.x * 16;
    int r = t & 15, cg = t >> 4;
    float acc[8] = {0.f,0.f,0.f,0.f,0.f,0.f,0.f,0.f};
    const float* Xh[3] = {X0, X1, X2};
    for (int h = 0; h < 3; ++h) {
        const float* X = Xh[h];
        stage_chunk(Ws, W + (size_t)h * FIN * HH, FIN * HH, t);
        for (int idx = t; idx < 16 * FIN; idx += 256) {
            int rr = idx / FIN, k = idx - rr * FIN;
            Xs[rr * 9 + k] = X[(size_t)(r0 + rr) * FIN + k];
        }
        __syncthreads();
        #pragma unroll
        for (int k = 0; k < FIN; ++k) {
            float xv = Xs[r * 9 + k];
            const float4 wa = *(const float4*)&Ws[k * HH + cg * 8];
            const float4 wb = *(const float4*)&Ws[k * HH + cg * 8 + 4];
            acc[0] += xv * wa.x; acc[1] += xv * wa.y;
            acc[2] += xv * wa.z; acc[3] += xv * wa.w;
            acc[4] += xv * wb.x; acc[5] += xv * wb.y;
            acc[6] += xv * wb.z; acc[7] += xv * wb.w;
        }
        __syncthreads();
    }
    size_t orow = (size_t)(r0 + r) * HH + cg * 8;
    float sv[8], mv[8];
    #pragma unroll
    for (int m = 0; m < 8; ++m) {
        float v = acc[m] + ldT(bias, cg * 8 + m);
        v = v > 0.f ? v : SLOPE * v;
        O[orow + m] = v;
        sv[m] = v * (1.0f / NPG);
        mv[m] = v;
    }
    pool_epilogue(g, r0 >> 8, 0, cg, r, sv, mv);
}

__global__ __launch_bounds__(256) void tagmm5_kernel(
        const float* X0, const float* X1, const float* X2,
        const void* W, const void* bias, float* O, float* g, const void* gamma) {
    __shared__ float Ws[FIN * HH];
    __shared__ float Xs[16 * 9];
    if (detect_bf(gamma))
        tagmm5_body<__hip_bfloat16>(X0, X1, X2, (const __hip_bfloat16*)W,
                                    (const __hip_bfloat16*)bias, O, g, Ws, Xs);
    else
        tagmm5_body<float>(X0, X1, X2, (const float*)W, (const float*)bias, O, g, Ws, Xs);
}

// ---------------- tagmm128 (+fused pool): 32 rows x 128 cols, Xs transposed ------------
template <typename T>
__device__ __forceinline__ void tagmm128_body(
        const float* __restrict__ X0, const float* __restrict__ X1,
        const float* __restrict__ X2,
        const T* __restrict__ W, const T* __restrict__ bias,
        float* __restrict__ O, float* g, int gc0, float* Ws, float* Xs) {
    int t = threadIdx.x;
    int r0 = blockIdx.x * 32;
    int rp = t & 15, cg = t >> 4;
    float acc[16];
    #pragma unroll
    for (int m = 0; m < 16; ++m) acc[m] = 0.f;
    const float* Xh[3] = {X0, X1, X2};
    for (int h = 0; h < 3; ++h) {
        const float* X = Xh[h];
        for (int k0 = 0; k0 < HH; k0 += 64) {
            stage_chunk(Ws, W + ((size_t)h * HH + k0) * HH, 64 * HH, t);
            for (int i = t; i < 32 * 16; i += 256) {
                int row = i & 31, kq = i >> 5;
                float4 v = *(const float4*)&X[(size_t)(r0 + row) * HH + k0 + kq * 4];
                Xs[(kq * 4 + 0) * 34 + row] = v.x;
                Xs[(kq * 4 + 1) * 34 + row] = v.y;
                Xs[(kq * 4 + 2) * 34 + row] = v.z;
                Xs[(kq * 4 + 3) * 34 + row] = v.w;
            }
            __syncthreads();
            #pragma unroll 8
            for (int k = 0; k < 64; ++k) {
                const float2 xv = *(const float2*)&Xs[k * 34 + rp * 2];
                const float4 wa = *(const float4*)&Ws[k * HH + cg * 8];
                const float4 wb = *(const float4*)&Ws[k * HH + cg * 8 + 4];
                acc[0] += xv.x * wa.x; acc[1] += xv.x * wa.y;
                acc[2] += xv.x * wa.z; acc[3] += xv.x * wa.w;
                acc[4] += xv.x * wb.x; acc[5] += xv.x * wb.y;
                acc[6] += xv.x * wb.z; acc[7] += xv.x * wb.w;
                acc[8]  += xv.y * wa.x; acc[9]  += xv.y * wa.y;
                acc[10] += xv.y * wa.z; acc[11] += xv.y * wa.w;
                acc[12] += xv.y * wb.x; acc[13] += xv.y * wb.y;
                acc[14] += xv.y * wb.z; acc[15] += xv.y * wb.w;
            }
            __syncthreads();
        }
    }
    float sv[8], mv[8];
    #pragma unroll
    for (int rr = 0; rr < 2; ++rr) {
        size_t orow = (size_t)(r0 + rp * 2 + rr) * HH + cg * 8;
        #pragma unroll
        for (int m = 0; m < 8; ++m) {
            float v = acc[rr * 8 + m] + ldT(bias, cg * 8 + m);
            v = v > 0.f ? v : SLOPE * v;
            O[orow + m] = v;
            if (rr == 0) { sv[m] = v * (1.0f / NPG); mv[m] = v; }
            else         { sv[m] += v * (1.0f / NPG); mv[m] = fmaxf(mv[m], v); }
        }
    }
    pool_epilogue(g, r0 >> 8, gc0, cg, rp, sv, mv);
}

__global__ __launch_bounds__(256) void tagmm128_kernel(
        const float* X0, const float* X1, const float* X2,
        const void* W, const void* bias, float* O, float* g, int gc0, const void* gamma) {
    __shared__ float Ws[64 * HH];
    __shared__ float Xs[64 * 34];
    if (detect_bf(gamma))
        tagmm128_body<__hip_bfloat16>(X0, X1, X2, (const __hip_bfloat16*)W,
                                      (const __hip_bfloat16*)bias, O, g, gc0, Ws, Xs);
    else
        tagmm128_body<float>(X0, X1, X2, (const float*)W, (const float*)bias,
                             O, g, gc0, Ws, Xs);
}

// ---------------- batchnorm v2: one-pass sum/sumsq (no vals[64] array / spills) ----------
__global__ void bn_kernel(float* __restrict__ g, const void* gamma, const void* beta) {
    int c = blockIdx.x * 128 + threadIdx.x;
    int bf = detect_bf(gamma);
    int ismax = (c & 255) >= 128;
    float s = 0.f, s2 = 0.f;
    #pragma unroll 8
    for (int b = 0; b < BB; ++b) {
        float raw = g[(size_t)b * H2 + c];
        float x = ismax ? dec_f(__float_as_uint(raw)) : raw;
        s += x; s2 += x * x;
    }
    float mu = s * (1.0f / BB);
    float var = fmaxf(s2 * (1.0f / BB) - mu * mu, 0.f);
    float rs = 1.0f / sqrtf(var + 1e-5f);
    float ga = loadin(gamma, c, bf), be = loadin(beta, c, bf);
    #pragma unroll 8
    for (int b = 0; b < BB; ++b) {
        float raw = g[(size_t)b * H2 + c];
        float x = ismax ? dec_f(__float_as_uint(raw)) : raw;
        g[(size_t)b * H2 + c] = (x - mu) * rs * ga + be;
    }
}

// ---------------- MLP layer GEMM: double-buffered prefetch ----------------
template <typename T>
__device__ __forceinline__ void mlp_layer_body(
        const float* __restrict__ X, const T* __restrict__ W, const T* __restrict__ bias,
        float* __restrict__ O, float* Xs0, float* Xs1, float* Ws0, float* Ws1) {
    int t = threadIdx.x;
    int col0 = blockIdx.x * 16;
    int r = t & 63, cg = t >> 6;
    float acc[4] = {0.f, 0.f, 0.f, 0.f};
    const float4* Xg = (const float4*)X;
    float4 xr[4]; float4 wr;
    int kr = t >> 2, c4 = t & 3;
    #pragma unroll
    for (int u = 0; u < 4; ++u) {
        int i = t + u * 256;
        xr[u] = Xg[(size_t)(i >> 4) * (H2 / 4) + (i & 15)];
    }
    wr = ldT4(W + (size_t)kr * H2 + col0 + c4 * 4);
    {
        #pragma unroll
        for (int u = 0; u < 4; ++u) {
            int i = t + u * 256;
            float* d = &Xs0[(i >> 4) * 65 + (i & 15) * 4];
            d[0] = xr[u].x; d[1] = xr[u].y; d[2] = xr[u].z; d[3] = xr[u].w;
        }
        float* d = &Ws0[kr * 16 + c4 * 4];
        d[0] = wr.x; d[1] = wr.y; d[2] = wr.z; d[3] = wr.w;
    }
    __syncthreads();
    for (int s = 0; s < 12; ++s) {
        if (s + 1 < 12) {
            int k0 = (s + 1) * 64;
            #pragma unroll
            for (int u = 0; u < 4; ++u) {
                int i = t + u * 256;
                xr[u] = Xg[(size_t)(i >> 4) * (H2 / 4) + (k0 >> 2) + (i & 15)];
            }
            wr = ldT4(W + (size_t)(k0 + kr) * H2 + col0 + c4 * 4);
        }
        const float* Xc = (s & 1) ? Xs1 : Xs0;
        const float* Wc = (s & 1) ? Ws1 : Ws0;
        #pragma unroll 8
        for (int k = 0; k < 64; ++k) {
            float xv = Xc[r * 65 + k];
            const float4 wv = *(const float4*)&Wc[k * 16 + cg * 4];
            acc[0] += xv * wv.x; acc[1] += xv * wv.y;
            acc[2] += xv * wv.z; acc[3] += xv * wv.w;
        }
        if (s + 1 < 12) {
            float* Xn = (s & 1) ? Xs0 : Xs1;
            float* Wn = (s & 1) ? Ws0 : Ws1;
            #pragma unroll
            for (int u = 0; u < 4; ++u) {
                int i = t + u * 256;
                float* d = &Xn[(i >> 4) * 65 + (i & 15) * 4];
                d[0] = xr[u].x; d[1] = xr[u].y; d[2] = xr[u].z; d[3] = xr[u].w;
            }
            float* d = &Wn[kr * 16 + c4 * 4];
            d[0] = wr.x; d[1] = wr.y; d[2] = wr.z; d[3] = wr.w;
            __syncthreads();
        }
    }
    size_t o = (size_t)r * H2 + col0 + cg * 4;
    #pragma unroll
    for (int m = 0; m < 4; ++m) {
        float v = acc[m] + ldT(bias, col0 + cg * 4 + m);
        O[o + m] = v > 0.f ? v : SLOPE * v;
    }
}

__global__ __launch_bounds__(256) void mlp_layer_kernel(
        const float* X, const void* W, size_t woff, const void* bias, size_t boff,
        float* O, const void* gamma) {
    __shared__ float Xs0[64 * 65], Xs1[64 * 65];
    __shared__ float Ws0[64 * 16], Ws1[64 * 16];
    if (detect_bf(gamma))
        mlp_layer_body<__hip_bfloat16>(X, (const __hip_bfloat16*)W + woff,
                                       (const __hip_bfloat16*)bias + boff, O,
                                       Xs0, Xs1, Ws0, Ws1);
    else
        mlp_layer_body<float>(X, (const float*)W + woff,
                              (const float*)bias + boff, O, Xs0, Xs1, Ws0, Ws1);
}

// ---------------- final dot: out[b] = X[b,:] . w + ob ----------------
__global__ void final_kernel(const float* __restrict__ X, const void* w, const void* ob,
                             void* out, const void* gamma) {
    int b = blockIdx.x, t = threadIdx.x;
    int bf = detect_bf(gamma);
    float p = 0.f;
    for (int j = t; j < H2; j += 256)
        p += X[(size_t)b * H2 + j] * loadin(w, j, bf);
    __shared__ float red[256];
    red[t] = p;
    __syncthreads();
    for (int s = 128; s > 0; s >>= 1) {
        if (t < s) red[t] += red[t + s];
        __syncthreads();
    }
    if (t == 0) {
        float v = red[0] + loadin(ob, 0, bf);
        if (bf) ((__hip_bfloat16*)out)[b] = __float2bfloat16(v);
        else    ((float*)out)[b] = v;
    }
}

extern "C" void kernel_launch(void* const* d_in, const int* in_sizes, int n_in,
                              void* d_out, int out_size, void* d_ws, size_t ws_size,
                              hipStream_t stream) {
    const void* x_in = d_in[0];
    const void* c1w = d_in[2];  const void* c1b = d_in[3];
    const void* c2w = d_in[4];  const void* c2b = d_in[5];
    const void* c3w = d_in[6];  const void* c3b = d_in[7];
    const void* gam = d_in[8];  const void* bet = d_in[9];
    const void* lw  = d_in[10]; const void* lb  = d_in[11];
    const void* ow  = d_in[12]; const void* obb = d_in[13];

    char* w = (char*)d_ws;
    float* xf = (float*)w;                   w += (size_t)NN * FIN * 4;
    unsigned char* nbr = (unsigned char*)w;  w += (size_t)NN * KNN;
    float* t5a = (float*)w;                  w += (size_t)NN * FIN * 4;
    float* t5b = (float*)w;                  w += (size_t)NN * FIN * 4;
    float* bufA = (float*)w;                 w += (size_t)NN * HH * 4;
    float* bufB = (float*)w;                 w += (size_t)NN * HH * 4;
    float* bufC = (float*)w;                 w += (size_t)NN * HH * 4;
    float* bufD = (float*)w;                 w += (size_t)NN * HH * 4;
    float* g = (float*)w;                    w += (size_t)BB * H2 * 4;
    float* mA = (float*)w;                   w += (size_t)BB * H2 * 4;
    float* mB = (float*)w;                   w += (size_t)BB * H2 * 4;

    float dinv = 1.0f / sqrtf((float)KNN);
    float nrm = dinv * dinv;

    cvt_kernel<<<(NN * FIN + 255) / 256, 256, 0, stream>>>(x_in, gam, xf, NN * FIN, g);
    knn_kernel<<<NN, 256, 0, stream>>>(xf, nbr);

    dim3 conv_grid32(NN / 32);
    dim3 agg_grid(BB, 4, 4);

    // ---- conv1 (Cin=5): hops, then fused matmul+pool ----
    agg5x2_kernel<<<BB, 256, 0, stream>>>(xf, nbr, t5a, t5b, nrm);
    tagmm5_kernel<<<NN / 16, 256, 0, stream>>>(xf, t5a, t5b, c1w, c1b, bufA, g, gam);

    // ---- conv2: bufA -> bufD (+pool @256) ----
    agg128_kernel<<<agg_grid, 256, 0, stream>>>(bufA, nbr, bufB, nrm);
    agg128_kernel<<<agg_grid, 256, 0, stream>>>(bufB, nbr, bufC, nrm);
    tagmm128_kernel<<<conv_grid32, 256, 0, stream>>>(bufA, bufB, bufC, c2w, c2b,
                                                     bufD, g, 256, gam);

    // ---- conv3: bufD -> bufC (+pool @512) ----
    agg128_kernel<<<agg_grid, 256, 0, stream>>>(bufD, nbr, bufA, nrm);
    agg128_kernel<<<agg_grid, 256, 0, stream>>>(bufA, nbr, bufB, nrm);
    tagmm128_kernel<<<conv_grid32, 256, 0, stream>>>(bufD, bufA, bufB, c3w, c3b,
                                                     bufC, g, 512, gam);

    // ---- batchnorm (decodes pool accumulators) ----
    bn_kernel<<<6, 128, 0, stream>>>(g, gam, bet);

    // ---- MLP: 5 GEMM layers, then final dot ----
    float* src = g;
    for (int i = 0; i < 5; ++i) {
        float* dst = (i % 2 == 0) ? mA : mB;
        mlp_layer_kernel<<<H2 / 16, 256, 0, stream>>>(src, lw, (size_t)i * H2 * H2,
                                                      lb, (size_t)i * H2, dst, gam);
        src = dst;
    }
    final_kernel<<<BB, 256, 0, stream>>>(src, ow, obb, d_out, gam);
}